// Round 2
// baseline (269.587 us; speedup 1.0000x reference)
//
#include <hip/hip_runtime.h>

#define OUT_W 1024
#define OUT_H 1024
#define BOXES 8   // boxes (rows) per block

// Native clang vector type — __builtin_nontemporal_store requires a vector of
// scalars, not HIP's struct-wrapped float4.
typedef float floatx4 __attribute__((ext_vector_type(4)));

// One block per 8 consecutive (b,n) boxes. 256 threads; per box each thread
// produces one float4 of vector_x and one float4 of vector_y (1024 elems/row).
//
// Why 8 boxes/block: with 1 box/block each thread stores only 32 B and the
// wave dies — per-block param-load latency + launch overhead dominate
// (~3 TB/s effective). Batching 8 boxes prefetches all params up front
// (wave-uniform -> s_load, amortized) and gives each thread 16 independent
// dwordx4 stores in flight, enough MLP to approach the ~6.6 TB/s the
// harness's own fill kernel achieves on this buffer.
__global__ __launch_bounds__(256)
void gv_kernel(const float* __restrict__ center,
               const float* __restrict__ wh,
               float* __restrict__ out_x,
               float* __restrict__ out_y,
               int BN)
{
    const int t    = threadIdx.x;
    const int base = blockIdx.x * BOXES;

    // ---- prefetch all per-box params (uniform addresses -> s_load batch) ----
    float cx[BOXES], cy[BOXES], Wb[BOXES], Hb[BOXES];
#pragma unroll
    for (int j = 0; j < BOXES; ++j) {
        const int bn = base + j;
        if (bn < BN) {
            const float2 c = reinterpret_cast<const float2*>(center)[bn];
            const float2 w = reinterpret_cast<const float2*>(wh)[bn];
            cx[j] = c.x; cy[j] = c.y; Wb[j] = w.x; Hb[j] = w.y;
        } else {
            cx[j] = 0.0f; cy[j] = 0.0f; Wb[j] = 0.0f; Hb[j] = 0.0f;
        }
    }

    const int   p0 = t * 4;
    const float pf[4] = { (float)(p0 + 0), (float)(p0 + 1),
                          (float)(p0 + 2), (float)(p0 + 3) };

#pragma unroll
    for (int j = 0; j < BOXES; ++j) {
        const int bn = base + j;
        if (bn >= BN) break;

        // kernel size = floor(W/2)*2 - 1 ; radius = floor((ks-1)/2) ;
        // sigma = floor(r/3) — fp32 exactly like the jnp reference
        const float ksw = floorf(Wb[j] * 0.5f) * 2.0f - 1.0f;
        const float rw  = floorf((ksw - 1.0f) * 0.5f);
        const float sw  = floorf(rw / 3.0f);
        const float ksh = floorf(Hb[j] * 0.5f) * 2.0f - 1.0f;
        const float rh  = floorf((ksh - 1.0f) * 0.5f);
        const float sh  = floorf(rh / 3.0f);

        const bool zero_box = ((cx[j] + cy[j]) + (Wb[j] + Hb[j])) == 0.0f;

        // SCALE = upscale/stride = 1.0 ; trunc toward zero as astype(int32)
        const float x = truncf(cx[j]);
        const float y = truncf(cy[j]);

        const float ul0 = x - rw;
        const float ul1 = y - rh;
        const float br0 = x + rw + 1.0f;
        const float br1 = y + rh + 1.0f;

        // is_point_in_img: inclusive upper bound
        const bool in_ul = (ul0 >= 0.0f) && (ul0 <= (float)OUT_W) &&
                           (ul1 >= 0.0f) && (ul1 <= (float)OUT_H);
        const bool in_br = (br0 >= 0.0f) && (br0 <= (float)OUT_W) &&
                           (br1 >= 0.0f) && (br1 <= (float)OUT_H);
        const bool active = (!zero_box) && (sw != 0.0f) && (sh != 0.0f) &&
                            (in_ul || in_br);

        // safe sigma (reference guards sig==0 inside exp even though the
        // mask kills it)
        const float ssw = (sw == 0.0f) ? 1.0f : sw;
        const float ssh = (sh == 0.0f) ? 1.0f : sh;
        const float iw  = -1.0f / (2.0f * ssw * ssw);
        const float ih  = -1.0f / (2.0f * ssh * ssh);

        floatx4 vx, vy;
#pragma unroll
        for (int i = 0; i < 4; ++i) {
            const float p  = pf[i];
            const float dx = p - x;
            const float dy = p - y;
            const bool mx = active && (p >= ul0) && (p < br0);
            const bool my = active && (p >= ul1) && (p < br1);
            vx[i] = mx ? __expf(dx * dx * iw) : 0.0f;
            vy[i] = my ? __expf(dy * dy * ih) : 0.0f;
        }

        const size_t row = (size_t)bn * (OUT_W / 4) + t;
        __builtin_nontemporal_store(vx, reinterpret_cast<floatx4*>(out_x) + row);
        __builtin_nontemporal_store(vy, reinterpret_cast<floatx4*>(out_y) + row);
    }
}

extern "C" void kernel_launch(void* const* d_in, const int* in_sizes, int n_in,
                              void* d_out, int out_size, void* d_ws, size_t ws_size,
                              hipStream_t stream) {
    const float* center = (const float*)d_in[0];  // [B,N,2]
    const float* wh     = (const float*)d_in[1];  // [B,N,2]
    float* out = (float*)d_out;                   // vector_x ++ vector_y, fp32

    const int BN = in_sizes[0] / 2;               // B*N = 32768
    float* out_x = out;
    float* out_y = out + (size_t)BN * OUT_W;

    const int grid = (BN + BOXES - 1) / BOXES;    // 4096 blocks
    gv_kernel<<<dim3(grid), dim3(256), 0, stream>>>(center, wh, out_x, out_y, BN);
}

// Round 3
// 254.205 us; speedup vs baseline: 1.0605x; 1.0605x over previous
//
#include <hip/hip_runtime.h>

#define OUT_W 1024
#define OUT_H 1024

// Strategy: the output is ~90% exact zeros (avg Gaussian window ~109/1024
// elems per row). Instead of having one kernel stream all 268 MB (measured
// ~2.9-5.5 TB/s effective), zero the buffer with hipMemsetAsync — which uses
// the runtime's fillBufferAligned path that demonstrably sustains ~6.3-6.6
// TB/s on this very buffer — and then splat only the nonzero windows
// (~28 MB of scattered-but-row-contiguous writes).
//
// One wave per box. Lanes 0..63 stride across the box's clamped x-window and
// y-window. All math is bit-identical to the previous (passing, absmax=0)
// fused kernel; zeros written by memset are exactly 0.0f as the reference.
__global__ __launch_bounds__(256)
void gv_splat(const float* __restrict__ center,
              const float* __restrict__ wh,
              float* __restrict__ out_x,
              float* __restrict__ out_y,
              int BN)
{
    const int wave = threadIdx.x >> 6;   // 4 waves/block
    const int lane = threadIdx.x & 63;
    const int bn   = blockIdx.x * 4 + wave;
    if (bn >= BN) return;

    const float2 c = reinterpret_cast<const float2*>(center)[bn];
    const float2 w = reinterpret_cast<const float2*>(wh)[bn];
    const float cx = c.x, cy = c.y, Wb = w.x, Hb = w.y;

    // kernel size = floor(W/2)*2 - 1 ; radius = floor((ks-1)/2) ;
    // sigma = floor(r/3) — fp32 exactly like the jnp reference
    const float ksw = floorf(Wb * 0.5f) * 2.0f - 1.0f;
    const float rw  = floorf((ksw - 1.0f) * 0.5f);
    const float sw  = floorf(rw / 3.0f);
    const float ksh = floorf(Hb * 0.5f) * 2.0f - 1.0f;
    const float rh  = floorf((ksh - 1.0f) * 0.5f);
    const float sh  = floorf(rh / 3.0f);

    const bool zero_box = ((cx + cy) + (Wb + Hb)) == 0.0f;

    // SCALE = upscale/stride = 1.0 ; trunc toward zero as astype(int32)
    const float x = truncf(cx);
    const float y = truncf(cy);

    const float ul0 = x - rw;
    const float ul1 = y - rh;
    const float br0 = x + rw + 1.0f;
    const float br1 = y + rh + 1.0f;

    // is_point_in_img: inclusive upper bound
    const bool in_ul = (ul0 >= 0.0f) && (ul0 <= (float)OUT_W) &&
                       (ul1 >= 0.0f) && (ul1 <= (float)OUT_H);
    const bool in_br = (br0 >= 0.0f) && (br0 <= (float)OUT_W) &&
                       (br1 >= 0.0f) && (br1 <= (float)OUT_H);
    const bool active = (!zero_box) && (sw != 0.0f) && (sh != 0.0f) &&
                        (in_ul || in_br);
    if (!active) return;   // memset already wrote the zeros

    const float iw = -1.0f / (2.0f * sw * sw);   // active => sw,sh != 0
    const float ih = -1.0f / (2.0f * sh * sh);

    // all of x, rw etc. are integer-valued floats well inside int range
    const int xs = max(0, (int)ul0);
    const int xe = min(OUT_W, (int)br0);
    const int ys = max(0, (int)ul1);
    const int ye = min(OUT_H, (int)br1);

    float* __restrict__ rowx = out_x + (size_t)bn * OUT_W;
    float* __restrict__ rowy = out_y + (size_t)bn * OUT_W;

    for (int p = xs + lane; p < xe; p += 64) {
        const float dx = (float)p - x;
        rowx[p] = __expf(dx * dx * iw);
    }
    for (int p = ys + lane; p < ye; p += 64) {
        const float dy = (float)p - y;
        rowy[p] = __expf(dy * dy * ih);
    }
}

extern "C" void kernel_launch(void* const* d_in, const int* in_sizes, int n_in,
                              void* d_out, int out_size, void* d_ws, size_t ws_size,
                              hipStream_t stream) {
    const float* center = (const float*)d_in[0];  // [B,N,2]
    const float* wh     = (const float*)d_in[1];  // [B,N,2]
    float* out = (float*)d_out;                   // vector_x ++ vector_y, fp32

    const int BN = in_sizes[0] / 2;               // B*N = 32768
    float* out_x = out;
    float* out_y = out + (size_t)BN * OUT_W;

    // Zero the whole output via the runtime's optimized fill path (~6.5 TB/s),
    // then splat only the nonzero Gaussian windows (~28 MB).
    hipMemsetAsync(d_out, 0, (size_t)out_size, stream);

    const int grid = (BN + 3) / 4;                // one wave per box
    gv_splat<<<dim3(grid), dim3(256), 0, stream>>>(center, wh, out_x, out_y, BN);
}